// Round 4
// baseline (14831.577 us; speedup 1.0000x reference)
//
#include <hip/hip_runtime.h>
#include <hip/hip_bf16.h>

#define NN 50000
#define NE 1600000
#define FIN 64
#define H 128
#define NL 5
#define NG 512
#define NC 10

typedef __hip_bfloat16 bf16;

// ws float-offset layout
#define OFF_H     0
#define OFF_MB    6400000
#define OFF_AGG   12800000
#define OFF_EW    19200000
#define OFF_W     20800000
#define OFF_WTIH  20881920
#define OFF_WTHH  20931072
#define OFF_BIH   20980224
#define OFF_BHH   20980608
#define OFF_D1W   20980992
#define OFF_D1B   21046528
#define OFF_D2W   21047040
#define OFF_D2B   21052160
#define OFF_POOL  21052176   // 65536 unsigned
#define OFF_FLAGS 21117712   // 16 ints
// total ~21.12M floats = 84.5 MB

__device__ __forceinline__ float loadF(const void* p, int idx, int f32){
    return f32 ? ((const float*)p)[idx]
               : __bfloat162float(((const bf16*)p)[idx]);
}

// flags[0]=ei is int64, flags[1]=batch is int64, flags[2]=floats are fp32
__global__ void k_detect(const unsigned* __restrict__ xw, const unsigned* __restrict__ eiw,
                         const unsigned* __restrict__ bw, int* __restrict__ flags){
    if (threadIdx.x == 0 && blockIdx.x == 0){
        int sane = 0;
        for (int k = 0; k < 64; ++k){
            unsigned w = xw[k*997];            // in-bounds for both widths
            unsigned e = (w >> 7) & 0xFF;      // exponent field of LOW halfword as bf16
            if (e >= 0x6C && e <= 0x8F) sane++;
        }
        flags[2] = (sane >= 48) ? 0 : 1;       // bf16 storage -> ~64 sane; fp32 -> ~9
        unsigned o1 = 0, o2 = 0;
        for (int k = 0; k < 32; ++k){
            o1 |= eiw[k*1400 + 1];             // odd words: int64 high-halves are 0
            o2 |= bw [k*1400 + 1];
        }
        flags[0] = (o1 == 0) ? 1 : 0;
        flags[1] = (o2 == 0) ? 1 : 0;
    }
}

__global__ void k_pad(const void* __restrict__ x, float* __restrict__ h,
                      const int* __restrict__ flags){
    int f32 = flags[2];
    int idx = blockIdx.x*256 + threadIdx.x;
    int n = idx >> 7, f = idx & 127;
    h[idx] = (f < FIN) ? loadF(x, n*FIN + f, f32) : 0.f;
}

__global__ void k_cvt_ew(const void* __restrict__ ew, float* __restrict__ ewf,
                         const int* __restrict__ flags){
    int f32 = flags[2];
    int i = blockIdx.x*256 + threadIdx.x;
    if (i < NE) ewf[i] = loadF(ew, i, f32);
}

// convert W(81920), d1w(65536), d1b(512), d2w(5120), d2b(10), bih(384), bhh(384)
__global__ void k_cvt_w(const void* W, const void* d1w, const void* d1b,
                        const void* d2w, const void* d2b,
                        const void* bih, const void* bhh,
                        float* Wf, float* d1wf, float* d1bf, float* d2wf, float* d2bf,
                        float* bihf, float* bhhf, const int* __restrict__ flags){
    int f32 = flags[2];
    int i = blockIdx.x*256 + threadIdx.x;
    if      (i < 81920)                 Wf  [i]         = loadF(W,   i,          f32);
    else if (i < 81920+65536)           d1wf[i-81920]   = loadF(d1w, i-81920,    f32);
    else if (i < 81920+65536+512)       d1bf[i-147456]  = loadF(d1b, i-147456,   f32);
    else if (i < 81920+65536+512+5120)  d2wf[i-147968]  = loadF(d2w, i-147968,   f32);
    else if (i < 153098)                d2bf[i-153088]  = loadF(d2b, i-153088,   f32);
    else if (i < 153098+384)            bihf[i-153098]  = loadF(bih, i-153098,   f32);
    else if (i < 153482+384)            bhhf[i-153482]  = loadF(bhh, i-153482,   f32);
}

// transpose GRU weights [384,128] -> [128,384]
__global__ void k_cvt_wt(const void* __restrict__ w_ih, const void* __restrict__ w_hh,
                         float* __restrict__ wt_ih, float* __restrict__ wt_hh,
                         const int* __restrict__ flags){
    int f32 = flags[2];
    int idx = blockIdx.x*256 + threadIdx.x;      // 0 .. 98303
    int which = idx / 49152;
    int r = idx % 49152;
    int jj = r / 128, k = r % 128;
    float v = loadF(which ? w_hh : w_ih, r, f32);
    (which ? wt_hh : wt_ih)[k*384 + jj] = v;
}

__global__ void k_init_pool(unsigned* __restrict__ p){
    p[blockIdx.x*256 + threadIdx.x] = 0x007FFFFFu;   // enc(-inf)
}

// mb[N,128] = h @ W_l
__global__ void k_mix(const float* __restrict__ h, const float* __restrict__ W,
                      float* __restrict__ mb){
    __shared__ float sh[16][128];
    int n0 = blockIdx.x * 16;
    int tid = threadIdx.x;
    for (int i = tid; i < 2048; i += 256)
        sh[i>>7][i&127] = h[(n0 + (i>>7))*H + (i&127)];
    __syncthreads();
    int c = tid & 127, half = tid >> 7;
    float acc[8] = {0,0,0,0,0,0,0,0};
    for (int k = 0; k < H; ++k) {
        float w = W[k*H + c];
        #pragma unroll
        for (int i = 0; i < 8; ++i) acc[i] += sh[half*8 + i][k] * w;
    }
    #pragma unroll
    for (int i = 0; i < 8; ++i) mb[(n0 + half*8 + i)*H + c] = acc[i];
}

// agg[dst] += m[src] * ew  (atomic scatter; 32 float4-lanes per edge)
__global__ void k_edge(const float* __restrict__ mb, const int* __restrict__ ei,
                       const float* __restrict__ ewf, float* __restrict__ agg,
                       const int* __restrict__ flags){
    int f64 = flags[0];
    int idx = blockIdx.x*256 + threadIdx.x;
    int e = idx >> 5, q = idx & 31;
    int src, dst;
    if (f64){ src = ei[2*e]; dst = ei[2*NE + 2*e]; }
    else    { src = ei[e];   dst = ei[NE + e];     }
    float w = ewf[e];
    const float4 v = *(const float4*)(mb + src*H + q*4);
    float* a = agg + dst*H + q*4;
    atomicAdd(a+0, v.x*w);
    atomicAdd(a+1, v.y*w);
    atomicAdd(a+2, v.z*w);
    atomicAdd(a+3, v.w*w);
}

// fused GRUCell: h = GRU(agg, h), in-place
__global__ void k_gru(float* __restrict__ h, const float* __restrict__ agg,
                      const float* __restrict__ wt_ih, const float* __restrict__ wt_hh,
                      const float* __restrict__ b_ih, const float* __restrict__ b_hh){
    __shared__ float sa[16][128], sh2[16][128];
    int n0 = blockIdx.x * 16;
    int tid = threadIdx.x;
    for (int i = tid; i < 2048; i += 256){
        int nn = i>>7, kk = i&127;
        sa[nn][kk]  = agg[(n0+nn)*H + kk];
        sh2[nn][kk] = h[(n0+nn)*H + kk];
    }
    __syncthreads();
    int j = tid & 127, half = tid >> 7;
    float gr[8], gz[8], gn[8], hr[8], hz[8], hn[8];
    {
        float bir = b_ih[j], biz = b_ih[H+j], bin_ = b_ih[2*H+j];
        float bhr = b_hh[j], bhz = b_hh[H+j], bhn  = b_hh[2*H+j];
        #pragma unroll
        for (int i = 0; i < 8; ++i){ gr[i]=bir; gz[i]=biz; gn[i]=bin_; hr[i]=bhr; hz[i]=bhz; hn[i]=bhn; }
    }
    for (int k = 0; k < H; ++k){
        float wir = wt_ih[k*384 + j], wiz = wt_ih[k*384 + H + j], win = wt_ih[k*384 + 2*H + j];
        float whr = wt_hh[k*384 + j], whz = wt_hh[k*384 + H + j], whn = wt_hh[k*384 + 2*H + j];
        #pragma unroll
        for (int i = 0; i < 8; ++i){
            float a = sa[half*8+i][k], hh = sh2[half*8+i][k];
            gr[i] += a*wir;  gz[i] += a*wiz;  gn[i] += a*win;
            hr[i] += hh*whr; hz[i] += hh*whz; hn[i] += hh*whn;
        }
    }
    #pragma unroll
    for (int i = 0; i < 8; ++i){
        int n = n0 + half*8 + i;
        float r  = 1.f/(1.f + __expf(-(gr[i]+hr[i])));
        float z  = 1.f/(1.f + __expf(-(gz[i]+hz[i])));
        float nt = tanhf(gn[i] + r*hn[i]);
        float ho = sh2[half*8+i][j];
        h[n*H + j] = (1.f - z)*nt + z*ho;
    }
}

// segment_max via order-preserving uint encoding + atomicMax
__global__ void k_pool(const float* __restrict__ h, const int* __restrict__ batch,
                       unsigned* __restrict__ pooled, const int* __restrict__ flags){
    int f64 = flags[1];
    int idx = blockIdx.x*256 + threadIdx.x;
    int n = idx >> 7, f = idx & 127;
    int g = f64 ? batch[2*n] : batch[n];
    unsigned u = __float_as_uint(h[idx]);
    u = (u & 0x80000000u) ? ~u : (u | 0x80000000u);
    atomicMax(pooled + g*H + f, u);
}

// MLP head: one block per graph.  OUTPUT IS FP32 (reference returns float32).
__global__ void k_head(const unsigned* __restrict__ pooled,
                       const float* __restrict__ d1w, const float* __restrict__ d1b,
                       const float* __restrict__ d2w, const float* __restrict__ d2b,
                       float* __restrict__ out){
    __shared__ float sp[128];
    __shared__ float shid[512];
    int g = blockIdx.x, tid = threadIdx.x;
    if (tid < 128){
        unsigned u = pooled[g*H + tid];
        sp[tid] = __uint_as_float((u & 0x80000000u) ? (u ^ 0x80000000u) : ~u);
    }
    __syncthreads();
    for (int o = tid; o < 512; o += 256){
        float acc = d1b[o];
        for (int k = 0; k < H; ++k) acc += sp[k] * d1w[o*H + k];
        shid[o] = fmaxf(acc, 0.f);
    }
    __syncthreads();
    if (tid < NC){
        float acc = d2b[tid];
        for (int o = 0; o < 512; ++o) acc += shid[o] * d2w[tid*512 + o];
        out[g*NC + tid] = acc;
    }
}

extern "C" void kernel_launch(void* const* d_in, const int* in_sizes, int n_in,
                              void* d_out, int out_size, void* d_ws, size_t ws_size,
                              hipStream_t stream){
    const void* x     = d_in[0];
    const int*  ei    = (const int*)d_in[1];
    const int*  batch = (const int*)d_in[2];
    const void* ew    = d_in[3];
    const void* W     = d_in[4];
    const void* wih   = d_in[5];
    const void* whh   = d_in[6];
    const void* bih   = d_in[7];
    const void* bhh   = d_in[8];
    const void* d1w   = d_in[9];
    const void* d1b   = d_in[10];
    const void* d2w   = d_in[11];
    const void* d2b   = d_in[12];
    float* out = (float*)d_out;

    float* ws = (float*)d_ws;
    float* h     = ws + OFF_H;
    float* mb    = ws + OFF_MB;
    float* agg   = ws + OFF_AGG;
    float* ewf   = ws + OFF_EW;
    float* Wf    = ws + OFF_W;
    float* wtih  = ws + OFF_WTIH;
    float* wthh  = ws + OFF_WTHH;
    float* bihf  = ws + OFF_BIH;
    float* bhhf  = ws + OFF_BHH;
    float* d1wf  = ws + OFF_D1W;
    float* d1bf  = ws + OFF_D1B;
    float* d2wf  = ws + OFF_D2W;
    float* d2bf  = ws + OFF_D2B;
    unsigned* pooled = (unsigned*)(ws + OFF_POOL);
    int* flags   = (int*)(ws + OFF_FLAGS);

    k_detect<<<1, 64, 0, stream>>>((const unsigned*)x, (const unsigned*)ei,
                                   (const unsigned*)batch, flags);
    k_cvt_ew<<<6250, 256, 0, stream>>>(ew, ewf, flags);
    k_cvt_w<<<602, 256, 0, stream>>>(W, d1w, d1b, d2w, d2b, bih, bhh,
                                     Wf, d1wf, d1bf, d2wf, d2bf, bihf, bhhf, flags);
    k_cvt_wt<<<384, 256, 0, stream>>>(wih, whh, wtih, wthh, flags);
    k_pad<<<25000, 256, 0, stream>>>(x, h, flags);
    k_init_pool<<<256, 256, 0, stream>>>(pooled);

    for (int l = 0; l < NL; ++l){
        hipMemsetAsync(agg, 0, (size_t)NN*H*sizeof(float), stream);
        k_mix<<<3125, 256, 0, stream>>>(h, Wf + (size_t)l*H*H, mb);
        k_edge<<<200000, 256, 0, stream>>>(mb, ei, ewf, agg, flags);
        k_gru<<<3125, 256, 0, stream>>>(h, agg, wtih, wthh, bihf, bhhf);
    }

    k_pool<<<25000, 256, 0, stream>>>(h, batch, pooled, flags);
    k_head<<<NG, 256, 0, stream>>>(pooled, d1wf, d1bf, d2wf, d2bf, out);
}

// Round 5
// 2225.899 us; speedup vs baseline: 6.6632x; 6.6632x over previous
//
#include <hip/hip_runtime.h>
#include <hip/hip_bf16.h>

#define NN 50000
#define NE 1600000
#define FIN 64
#define H 128
#define NL 5
#define NG 512
#define NC 10

// ws float-offset layout (total ~16.2M floats = 65 MB)
#define OFF_H     0
#define OFF_T     6400000
#define OFF_CUR   12800000   // 50016 ints (counts -> starts -> ends)
#define OFF_CSRS  12850016   // 1.6M ints  (src per CSR slot)
#define OFF_CSRW  14450016   // 1.6M floats (weight per CSR slot)
#define OFF_WTIH  16050016   // 49152
#define OFF_WTHH  16099168   // 49152
#define OFF_POOL  16148320   // 65536 unsigned

// ---------- CSR build (once per call, reused by all 5 layers) ----------

__global__ void k_hist(const int* __restrict__ ei, int* __restrict__ cnt){
    int e = blockIdx.x*256 + threadIdx.x;
    if (e < NE) atomicAdd(&cnt[ei[NE + e]], 1);
}

// single-block exclusive scan of cnt[0..NN) in-place (counts -> starts)
__global__ void k_scan(int* __restrict__ cur){
    __shared__ int s[1024];
    int t = threadIdx.x;
    const int CH = 49;                       // 1024*49 >= 50000
    int base = t*CH;
    int m = NN - base; if (m > CH) m = CH; if (m < 0) m = 0;
    int sum = 0;
    for (int i = 0; i < m; ++i) sum += cur[base + i];
    s[t] = sum; __syncthreads();
    for (int off = 1; off < 1024; off <<= 1){
        int v = (t >= off) ? s[t - off] : 0; __syncthreads();
        s[t] += v; __syncthreads();
    }
    int run = s[t] - sum;                    // exclusive prefix
    for (int i = 0; i < m; ++i){
        int c = cur[base + i];               // own range: read-before-write safe
        cur[base + i] = run;
        run += c;
    }
}

// scatter edges into buckets; cur[n] advances from start_n to end_n
__global__ void k_fill(const int* __restrict__ ei, const float* __restrict__ ew,
                       int* __restrict__ cur, int* __restrict__ csrs,
                       float* __restrict__ csrw){
    int e = blockIdx.x*256 + threadIdx.x;
    if (e >= NE) return;
    int src = ei[e], dst = ei[NE + e];
    int pos = atomicAdd(&cur[dst], 1);
    csrs[pos] = src;
    csrw[pos] = ew[e];
}

// ---------- one-time prep ----------

__global__ void k_pad(const float* __restrict__ x, float* __restrict__ h){
    int idx = blockIdx.x*256 + threadIdx.x;
    int n = idx >> 7, f = idx & 127;
    h[idx] = (f < FIN) ? x[n*FIN + f] : 0.f;
}

// transpose GRU weights [384,128] -> [128,384]
__global__ void k_cvt_wt(const float* __restrict__ w_ih, const float* __restrict__ w_hh,
                         float* __restrict__ wt_ih, float* __restrict__ wt_hh){
    int idx = blockIdx.x*256 + threadIdx.x;      // 0 .. 98303
    int which = idx / 49152;
    int r = idx % 49152;
    int jj = r / 128, k = r % 128;
    if (which == 0) wt_ih[k*384 + jj] = w_ih[r];
    else            wt_hh[k*384 + jj] = w_hh[r];
}

__global__ void k_init_pool(unsigned* __restrict__ p){
    p[blockIdx.x*256 + threadIdx.x] = 0x007FFFFFu;   // enc(-inf)
}

// ---------- per-layer ----------

// pull aggregation: t[n] = sum_{e:dst=n} ew[e] * h[src[e]]   (no atomics)
// one 64-lane wave per node; lane owns features [2*lane, 2*lane+1]
__global__ void k_agg(const float* __restrict__ h, const int* __restrict__ cur,
                      const int* __restrict__ csrs, const float* __restrict__ csrw,
                      float* __restrict__ t){
    int wave = blockIdx.x*4 + (threadIdx.x >> 6);
    if (wave >= NN) return;
    int lane = threadIdx.x & 63;
    int start = (wave == 0) ? 0 : cur[wave - 1];
    int end   = cur[wave];
    float ax = 0.f, ay = 0.f;
    for (int base = start; base < end; base += 64){
        int i = base + lane;
        int sv = 0; float wv = 0.f;
        if (i < end){ sv = csrs[i]; wv = csrw[i]; }
        int m = end - base; if (m > 64) m = 64;
        for (int j = 0; j < m; ++j){
            int   s = __shfl(sv, j);
            float w = __shfl(wv, j);
            const float2 v = *(const float2*)(h + s*H + lane*2);
            ax += w*v.x; ay += w*v.y;
        }
    }
    float2 o; o.x = ax; o.y = ay;
    *(float2*)(t + wave*H + lane*2) = o;
}

// in-place mix: t_tile = t_tile @ W_l   (row-local, 16 rows per block)
__global__ void k_mix(float* __restrict__ t, const float* __restrict__ W){
    __shared__ float sh[16][128];
    int n0 = blockIdx.x * 16;
    int tid = threadIdx.x;
    for (int i = tid; i < 2048; i += 256)
        sh[i>>7][i&127] = t[(n0 + (i>>7))*H + (i&127)];
    __syncthreads();
    int c = tid & 127, half = tid >> 7;
    float acc[8] = {0,0,0,0,0,0,0,0};
    for (int k = 0; k < H; ++k) {
        float w = W[k*H + c];
        #pragma unroll
        for (int i = 0; i < 8; ++i) acc[i] += sh[half*8 + i][k] * w;
    }
    #pragma unroll
    for (int i = 0; i < 8; ++i) t[(n0 + half*8 + i)*H + c] = acc[i];
}

// fused GRUCell: h = GRU(t, h), in-place
__global__ void k_gru(float* __restrict__ h, const float* __restrict__ agg,
                      const float* __restrict__ wt_ih, const float* __restrict__ wt_hh,
                      const float* __restrict__ b_ih, const float* __restrict__ b_hh){
    __shared__ float sa[16][128], sh2[16][128];
    int n0 = blockIdx.x * 16;
    int tid = threadIdx.x;
    for (int i = tid; i < 2048; i += 256){
        int nn = i>>7, kk = i&127;
        sa[nn][kk]  = agg[(n0+nn)*H + kk];
        sh2[nn][kk] = h[(n0+nn)*H + kk];
    }
    __syncthreads();
    int j = tid & 127, half = tid >> 7;
    float gr[8], gz[8], gn[8], hr[8], hz[8], hn[8];
    {
        float bir = b_ih[j], biz = b_ih[H+j], bin_ = b_ih[2*H+j];
        float bhr = b_hh[j], bhz = b_hh[H+j], bhn  = b_hh[2*H+j];
        #pragma unroll
        for (int i = 0; i < 8; ++i){ gr[i]=bir; gz[i]=biz; gn[i]=bin_; hr[i]=bhr; hz[i]=bhz; hn[i]=bhn; }
    }
    for (int k = 0; k < H; ++k){
        float wir = wt_ih[k*384 + j], wiz = wt_ih[k*384 + H + j], win = wt_ih[k*384 + 2*H + j];
        float whr = wt_hh[k*384 + j], whz = wt_hh[k*384 + H + j], whn = wt_hh[k*384 + 2*H + j];
        #pragma unroll
        for (int i = 0; i < 8; ++i){
            float a = sa[half*8+i][k], hh = sh2[half*8+i][k];
            gr[i] += a*wir;  gz[i] += a*wiz;  gn[i] += a*win;
            hr[i] += hh*whr; hz[i] += hh*whz; hn[i] += hh*whn;
        }
    }
    #pragma unroll
    for (int i = 0; i < 8; ++i){
        int n = n0 + half*8 + i;
        float r  = 1.f/(1.f + __expf(-(gr[i]+hr[i])));
        float z  = 1.f/(1.f + __expf(-(gz[i]+hz[i])));
        float nt = tanhf(gn[i] + r*hn[i]);
        float ho = sh2[half*8+i][j];
        h[n*H + j] = (1.f - z)*nt + z*ho;
    }
}

// ---------- tail ----------

__global__ void k_pool(const float* __restrict__ h, const int* __restrict__ batch,
                       unsigned* __restrict__ pooled){
    int idx = blockIdx.x*256 + threadIdx.x;
    int n = idx >> 7, f = idx & 127;
    int g = batch[n];
    unsigned u = __float_as_uint(h[idx]);
    u = (u & 0x80000000u) ? ~u : (u | 0x80000000u);
    atomicMax(pooled + g*H + f, u);
}

__global__ void k_head(const unsigned* __restrict__ pooled,
                       const float* __restrict__ d1w, const float* __restrict__ d1b,
                       const float* __restrict__ d2w, const float* __restrict__ d2b,
                       float* __restrict__ out){
    __shared__ float sp[128];
    __shared__ float shid[512];
    int g = blockIdx.x, tid = threadIdx.x;
    if (tid < 128){
        unsigned u = pooled[g*H + tid];
        sp[tid] = __uint_as_float((u & 0x80000000u) ? (u ^ 0x80000000u) : ~u);
    }
    __syncthreads();
    for (int o = tid; o < 512; o += 256){
        float acc = d1b[o];
        for (int k = 0; k < H; ++k) acc += sp[k] * d1w[o*H + k];
        shid[o] = fmaxf(acc, 0.f);
    }
    __syncthreads();
    if (tid < NC){
        float acc = d2b[tid];
        for (int o = 0; o < 512; ++o) acc += shid[o] * d2w[tid*512 + o];
        out[g*NC + tid] = acc;
    }
}

extern "C" void kernel_launch(void* const* d_in, const int* in_sizes, int n_in,
                              void* d_out, int out_size, void* d_ws, size_t ws_size,
                              hipStream_t stream){
    const float* x     = (const float*)d_in[0];
    const int*   ei    = (const int*)d_in[1];
    const int*   batch = (const int*)d_in[2];
    const float* ew    = (const float*)d_in[3];
    const float* W     = (const float*)d_in[4];
    const float* wih   = (const float*)d_in[5];
    const float* whh   = (const float*)d_in[6];
    const float* bih   = (const float*)d_in[7];
    const float* bhh   = (const float*)d_in[8];
    const float* d1w   = (const float*)d_in[9];
    const float* d1b   = (const float*)d_in[10];
    const float* d2w   = (const float*)d_in[11];
    const float* d2b   = (const float*)d_in[12];
    float* out = (float*)d_out;

    float* ws   = (float*)d_ws;
    float* h    = ws + OFF_H;
    float* t    = ws + OFF_T;
    int*   cur  = (int*)(ws + OFF_CUR);
    int*   csrs = (int*)(ws + OFF_CSRS);
    float* csrw = ws + OFF_CSRW;
    float* wtih = ws + OFF_WTIH;
    float* wthh = ws + OFF_WTHH;
    unsigned* pooled = (unsigned*)(ws + OFF_POOL);

    // CSR build (reused by all layers)
    hipMemsetAsync(cur, 0, (size_t)NN*sizeof(int), stream);
    k_hist<<<6250, 256, 0, stream>>>(ei, cur);
    k_scan<<<1, 1024, 0, stream>>>(cur);
    k_fill<<<6250, 256, 0, stream>>>(ei, ew, cur, csrs, csrw);

    k_cvt_wt<<<384, 256, 0, stream>>>(wih, whh, wtih, wthh);
    k_pad<<<25000, 256, 0, stream>>>(x, h);
    k_init_pool<<<256, 256, 0, stream>>>(pooled);

    for (int l = 0; l < NL; ++l){
        k_agg<<<12500, 256, 0, stream>>>(h, cur, csrs, csrw, t);
        k_mix<<<3125, 256, 0, stream>>>(t, W + (size_t)l*H*H);
        k_gru<<<3125, 256, 0, stream>>>(h, t, wtih, wthh, bih, bhh);
    }

    k_pool<<<25000, 256, 0, stream>>>(h, batch, pooled);
    k_head<<<NG, 256, 0, stream>>>(pooled, d1w, d1b, d2w, d2b, out);
}

// Round 6
// 1568.598 us; speedup vs baseline: 9.4553x; 1.4190x over previous
//
#include <hip/hip_runtime.h>
#include <hip/hip_bf16.h>

#define NN 50000
#define NE 1600000
#define FIN 64
#define H 128
#define NL 5
#define NG 512
#define NC 10

typedef __attribute__((ext_vector_type(8))) short short8;
typedef __attribute__((ext_vector_type(4))) float f32x4;

// ws float-offset layout (total ~16.27M floats = 65 MB)
#define OFF_H     0
#define OFF_T     6400000
#define OFF_CUR   12800000   // 50016 ints (counts -> starts -> ends)
#define OFF_CSRS  12850016   // 1.6M ints
#define OFF_CSRW  14450016   // 1.6M floats
#define OFF_POOL  16050016   // 65536 unsigned
#define OFF_FWF   16115552   // 245760 shorts (5 layers x 128x384 bf16 frag)
#define OFF_FWHH  16238432   // 49152 shorts

__device__ __forceinline__ short rne_bf16(float f){
    unsigned u = __float_as_uint(f);
    unsigned r = (u + 0x7FFFu + ((u >> 16) & 1u)) >> 16;
    return (short)r;
}

// ---------- CSR build ----------

__global__ void k_hist(const int* __restrict__ ei, int* __restrict__ cnt){
    int e = blockIdx.x*256 + threadIdx.x;
    if (e < NE) atomicAdd(&cnt[ei[NE + e]], 1);
}

__global__ void k_scan(int* __restrict__ cur){
    __shared__ int s[1024];
    int t = threadIdx.x;
    const int CH = 49;
    int base = t*CH;
    int m = NN - base; if (m > CH) m = CH; if (m < 0) m = 0;
    int sum = 0;
    for (int i = 0; i < m; ++i) sum += cur[base + i];
    s[t] = sum; __syncthreads();
    for (int off = 1; off < 1024; off <<= 1){
        int v = (t >= off) ? s[t - off] : 0; __syncthreads();
        s[t] += v; __syncthreads();
    }
    int run = s[t] - sum;
    for (int i = 0; i < m; ++i){
        int c = cur[base + i];
        cur[base + i] = run;
        run += c;
    }
}

__global__ void k_fill(const int* __restrict__ ei, const float* __restrict__ ew,
                       int* __restrict__ cur, int* __restrict__ csrs,
                       float* __restrict__ csrw){
    int e = blockIdx.x*256 + threadIdx.x;
    if (e >= NE) return;
    int src = ei[e], dst = ei[NE + e];
    int pos = atomicAdd(&cur[dst], 1);
    csrs[pos] = src;
    csrw[pos] = ew[e];
}

// ---------- one-time prep ----------

__global__ void k_pad(const float* __restrict__ x, float* __restrict__ h){
    int idx = blockIdx.x*256 + threadIdx.x;
    int n = idx >> 7, f = idx & 127;
    h[idx] = (f < FIN) ? x[n*FIN + f] : 0.f;
}

// fragWf[l] = bf16-frag( W_l @ w_ih^T )   [K=128][N=384]
// frag slot for (k,n): lane = ((k>>3)&3)*16 + (n&15), j = k&7, tile = (n>>4)*4 + (k>>5)
__global__ void k_fuse(const float* __restrict__ W, const float* __restrict__ wih,
                       short* __restrict__ fwf){
    int idx = blockIdx.x*256 + threadIdx.x;   // 0..245759
    int l = idx / 49152;
    int r = idx % 49152;
    int k = r / 384, n = r % 384;
    const float* wl = W + l*16384 + k*128;
    const float* wi = wih + n*128;
    float acc = 0.f;
    for (int c = 0; c < 128; ++c) acc += wl[c]*wi[c];
    int lane = ((k>>3)&3)*16 + (n&15);
    fwf[l*49152 + (((n>>4)*4 + (k>>5))*64 + lane)*8 + (k&7)] = rne_bf16(acc);
}

// fragWhh = bf16-frag( w_hh^T )  [K=128][N=384]
__global__ void k_cvt_whh(const float* __restrict__ whh, short* __restrict__ fwhh){
    int idx = blockIdx.x*256 + threadIdx.x;   // 0..49151
    int k = idx / 384, n = idx % 384;
    float v = whh[n*128 + k];
    int lane = ((k>>3)&3)*16 + (n&15);
    fwhh[(((n>>4)*4 + (k>>5))*64 + lane)*8 + (k&7)] = rne_bf16(v);
}

__global__ void k_init_pool(unsigned* __restrict__ p){
    p[blockIdx.x*256 + threadIdx.x] = 0x007FFFFFu;
}

// ---------- per-layer ----------

// pull aggregation: t[n] = sum ew * h[src]
__global__ void k_agg(const float* __restrict__ h, const int* __restrict__ cur,
                      const int* __restrict__ csrs, const float* __restrict__ csrw,
                      float* __restrict__ t){
    int wave = blockIdx.x*4 + (threadIdx.x >> 6);
    if (wave >= NN) return;
    int lane = threadIdx.x & 63;
    int start = (wave == 0) ? 0 : cur[wave - 1];
    int end   = cur[wave];
    float ax = 0.f, ay = 0.f;
    for (int base = start; base < end; base += 64){
        int i = base + lane;
        int sv = 0; float wv = 0.f;
        if (i < end){ sv = csrs[i]; wv = csrw[i]; }
        int m = end - base; if (m > 64) m = 64;
        for (int j = 0; j < m; ++j){
            int   s = __shfl(sv, j);
            float w = __shfl(wv, j);
            const float2 v = *(const float2*)(h + s*H + lane*2);
            ax += w*v.x; ay += w*v.y;
        }
    }
    float2 o; o.x = ax; o.y = ay;
    *(float2*)(t + wave*H + lane*2) = o;
}

// MFMA GRU: gi = t@Wf_l + b_ih ; gh = h@whh^T + b_hh ; h = GRU-update (in place)
// block = 16 nodes; waves 0,1 -> gi cols [0,384); waves 2,3 -> gh cols [0,384)
__global__ __launch_bounds__(256)
void k_gruM(float* __restrict__ h, const float* __restrict__ t,
            const short* __restrict__ fwf, const short* __restrict__ fwhh,
            const float* __restrict__ b_ih, const float* __restrict__ b_hh){
    __shared__ float sg[16][772];
    int tid = threadIdx.x;
    int n0 = blockIdx.x * 16;
    int wave = tid >> 6, lane = tid & 63;
    int lane_lo = lane & 15, quad = lane >> 4;
    const float* A = (wave < 2) ? t : h;
    const short* B = (wave < 2) ? fwf : fwhh;
    int wv = (wave < 2) ? wave : wave - 2;     // col half: [wv*192, wv*192+192)
    int arow = n0 + lane_lo;

    f32x4 acc[12];
    #pragma unroll
    for (int i = 0; i < 12; ++i) acc[i] = (f32x4){0.f,0.f,0.f,0.f};

    #pragma unroll
    for (int kt = 0; kt < 4; ++kt){
        const float* ap = A + arow*H + kt*32 + quad*8;
        short8 af;
        #pragma unroll
        for (int j = 0; j < 8; ++j) af[j] = rne_bf16(ap[j]);
        const short* bp = B + (wv*48 + kt)*512 + lane*8;
        #pragma unroll
        for (int nt = 0; nt < 12; ++nt){
            short8 bf = *(const short8*)(bp + nt*2048);
            acc[nt] = __builtin_amdgcn_mfma_f32_16x16x32_bf16(af, bf, acc[nt], 0, 0, 0);
        }
    }

    int cwb = (wave < 2) ? wave*192 : 384 + (wave - 2)*192;
    #pragma unroll
    for (int nt = 0; nt < 12; ++nt){
        int col = cwb + nt*16 + lane_lo;
        #pragma unroll
        for (int r = 0; r < 4; ++r)
            sg[quad*4 + r][col] = acc[nt][r];
    }
    __syncthreads();

    int er = tid >> 4, j0 = (tid & 15) * 8;
    float* hp = h + (n0 + er)*H + j0;
    #pragma unroll
    for (int i = 0; i < 8; ++i){
        int j = j0 + i;
        float gir = sg[er][j]       + b_ih[j];
        float giz = sg[er][128 + j] + b_ih[128 + j];
        float gin = sg[er][256 + j] + b_ih[256 + j];
        float ghr = sg[er][384 + j]       + b_hh[j];
        float ghz = sg[er][512 + j]       + b_hh[128 + j];
        float ghn = sg[er][640 + j]       + b_hh[256 + j];
        float rr = 1.f/(1.f + __expf(-(gir + ghr)));
        float zz = 1.f/(1.f + __expf(-(giz + ghz)));
        float nn = tanhf(gin + rr*ghn);
        float ho = hp[i];
        hp[i] = (1.f - zz)*nn + zz*ho;
    }
}

// ---------- tail ----------

__global__ void k_pool(const float* __restrict__ h, const int* __restrict__ batch,
                       unsigned* __restrict__ pooled){
    int idx = blockIdx.x*256 + threadIdx.x;
    int n = idx >> 7, f = idx & 127;
    int g = batch[n];
    unsigned u = __float_as_uint(h[idx]);
    u = (u & 0x80000000u) ? ~u : (u | 0x80000000u);
    atomicMax(pooled + g*H + f, u);
}

__global__ void k_head(const unsigned* __restrict__ pooled,
                       const float* __restrict__ d1w, const float* __restrict__ d1b,
                       const float* __restrict__ d2w, const float* __restrict__ d2b,
                       float* __restrict__ out){
    __shared__ float sp[128];
    __shared__ float shid[512];
    int g = blockIdx.x, tid = threadIdx.x;
    if (tid < 128){
        unsigned u = pooled[g*H + tid];
        sp[tid] = __uint_as_float((u & 0x80000000u) ? (u ^ 0x80000000u) : ~u);
    }
    __syncthreads();
    for (int o = tid; o < 512; o += 256){
        float acc = d1b[o];
        for (int k = 0; k < H; ++k) acc += sp[k] * d1w[o*H + k];
        shid[o] = fmaxf(acc, 0.f);
    }
    __syncthreads();
    if (tid < NC){
        float acc = d2b[tid];
        for (int o = 0; o < 512; ++o) acc += shid[o] * d2w[tid*512 + o];
        out[g*NC + tid] = acc;
    }
}

extern "C" void kernel_launch(void* const* d_in, const int* in_sizes, int n_in,
                              void* d_out, int out_size, void* d_ws, size_t ws_size,
                              hipStream_t stream){
    const float* x     = (const float*)d_in[0];
    const int*   ei    = (const int*)d_in[1];
    const int*   batch = (const int*)d_in[2];
    const float* ew    = (const float*)d_in[3];
    const float* W     = (const float*)d_in[4];
    const float* wih   = (const float*)d_in[5];
    const float* whh   = (const float*)d_in[6];
    const float* bih   = (const float*)d_in[7];
    const float* bhh   = (const float*)d_in[8];
    const float* d1w   = (const float*)d_in[9];
    const float* d1b   = (const float*)d_in[10];
    const float* d2w   = (const float*)d_in[11];
    const float* d2b   = (const float*)d_in[12];
    float* out = (float*)d_out;

    float* ws   = (float*)d_ws;
    float* h    = ws + OFF_H;
    float* t    = ws + OFF_T;
    int*   cur  = (int*)(ws + OFF_CUR);
    int*   csrs = (int*)(ws + OFF_CSRS);
    float* csrw = ws + OFF_CSRW;
    unsigned* pooled = (unsigned*)(ws + OFF_POOL);
    short* fwf  = (short*)(ws + OFF_FWF);
    short* fwhh = (short*)(ws + OFF_FWHH);

    hipMemsetAsync(cur, 0, (size_t)NN*sizeof(int), stream);
    k_hist<<<6250, 256, 0, stream>>>(ei, cur);
    k_scan<<<1, 1024, 0, stream>>>(cur);
    k_fill<<<6250, 256, 0, stream>>>(ei, ew, cur, csrs, csrw);

    k_fuse<<<960, 256, 0, stream>>>(W, wih, fwf);
    k_cvt_whh<<<192, 256, 0, stream>>>(whh, fwhh);
    k_pad<<<25000, 256, 0, stream>>>(x, h);
    k_init_pool<<<256, 256, 0, stream>>>(pooled);

    for (int l = 0; l < NL; ++l){
        k_agg<<<12500, 256, 0, stream>>>(h, cur, csrs, csrw, t);
        k_gruM<<<3125, 256, 0, stream>>>(h, t, fwf + (size_t)l*49152, fwhh, bih, bhh);
    }

    k_pool<<<25000, 256, 0, stream>>>(h, batch, pooled);
    k_head<<<NG, 256, 0, stream>>>(pooled, d1w, d1b, d2w, d2b, out);
}